// Round 2
// baseline (10189.321 us; speedup 1.0000x reference)
//
#include <hip/hip_runtime.h>
#include <stdint.h>

// Problem constants
#define B_  256
#define S_  512
#define E_  100
#define H_  512
#define G_  2048          // 4H
#define KH  512           // h part of K
#define KX  128           // padded x part of K
#define K_  640           // KH + KX

typedef _Float16 half8 __attribute__((ext_vector_type(8)));
typedef float    f32x4 __attribute__((ext_vector_type(4)));

union V16 { f32x4 f; half8 h; unsigned long long q[2]; };

static __device__ __forceinline__ half8 h8(f32x4 v) { V16 u; u.f = v; return u.h; }

// ws layout (bytes)
#define OFF_WC   0u          // [G][K_] f16      : 2,621,440
#define OFF_HBUF 2621440u    // [2][B][H] f16    :   524,288
#define OFF_XBUF 3145728u    // [S][B][KX] f16   : 33,554,432
#define OFF_BIAS 36700160u   // [G] f32          :     8,192
#define OFF_FLAG 36708352u   // [16][16][4] u32  :     4,096
#define WS_NEED  36712448u

// ---------------------------------------------------------------- prep: W + bias
__global__ void prep_wc(const float* __restrict__ Wih, const float* __restrict__ Whh,
                        const float* __restrict__ bih, const float* __restrict__ bhh,
                        _Float16* __restrict__ Wc, float* __restrict__ bias) {
    int idx = blockIdx.x * 256 + threadIdx.x;     // < G_*K_
    int g = idx / K_;
    int k = idx - g * K_;
    float v = 0.f;
    if (k < KH)            v = Whh[g * KH + k];
    else if (k < KH + E_)  v = Wih[g * E_ + (k - KH)];
    Wc[idx] = (_Float16)v;
    if (k == 0) bias[g] = bih[g] + bhh[g];
}

// ---------------------------------------------------------------- prep: embed gather
__global__ void prep_x(const int* __restrict__ sent, const float* __restrict__ emb,
                       _Float16* __restrict__ xbuf) {
    size_t idx = (size_t)blockIdx.x * 256 + threadIdx.x;  // < S_*B_*KX = 2^24
    int k = (int)(idx & (KX - 1));
    int b = (int)((idx >> 7) & (B_ - 1));
    int t = (int)(idx >> 15);
    int tok = sent[b * S_ + t];
    float v = (k < E_) ? emb[(size_t)tok * E_ + k] : 0.f;
    xbuf[idx] = (_Float16)v;
}

// ---------------------------------------------------------------- persistent LSTM
// 256 blocks = 16 batch-rows x 16 hcol-tiles. Block owns [16 batch x 32 hcol] of
// h/c. W slice (128 gate-rows x 640 K, f16) pinned in VGPRs via asm. All
// cross-block traffic is agent-scope atomics (LLC-direct, sc1) -> no cache
// invalidates anywhere in the loop.
__global__ __launch_bounds__(256, 1) void lstm_persist(
    const _Float16* __restrict__ Wc, _Float16* __restrict__ hbuf,
    const _Float16* __restrict__ xbuf, const float* __restrict__ bias,
    unsigned int* __restrict__ flags, float* __restrict__ out)
{
    const int tid = threadIdx.x;
    const int L   = tid & 63;
    const int w   = tid >> 6;          // wave = gate type (0:i 1:f 2:g 3:o)
    // XCD-aware swizzle: batch-row r's 16 col-blocks share one XCD (perf heuristic)
    const int bx  = blockIdx.x;
    const int xcd = bx & 7;
    const int kk_ = bx >> 3;           // 0..31
    const int r   = (xcd << 1) | (kk_ >> 4);   // batch-row 0..15
    const int c   = kk_ & 15;                  // hcol-tile 0..15
    const int brow0 = r << 4;          // 16 batches
    const int hcol0 = c << 5;          // 32 h cols

    // swizzled h A-tile: [16 rows][512 halfs], granule(16B) g at row -> slot g^(row&7)
    __shared__ __align__(16) _Float16 Alds[16 * 512];
    __shared__ float gbuf[4][16][33];          // [type][batch][hcol], padded

    // ---- W preload: 2 ntiles x 20 ktiles x 16B, PINNED in VGPRs
    f32x4 bfrag[2][20];
#pragma unroll
    for (int n = 0; n < 2; ++n) {
        const _Float16* gp = Wc + (size_t)((w << 9) + hcol0 + (n << 4) + (L & 15)) * K_
                                + ((L >> 4) << 3);
#pragma unroll
        for (int kt = 0; kt < 20; ++kt)
            bfrag[n][kt] = *reinterpret_cast<const f32x4*>(gp + kt * 32);
    }
#pragma unroll
    for (int n = 0; n < 2; ++n)
#pragma unroll
        for (int kt = 0; kt < 20; ++kt)
            asm volatile("" : "+v"(bfrag[n][kt]));   // asm result can't be rematerialized

    // ---- per-thread cell-state mapping: thread owns h/c values v0=2*tid, v0+1
    const int v0 = tid << 1;
    const int bl = v0 >> 5;            // batch-within-tile 0..15
    const int j0 = v0 & 31;            // hcol-within-tile (even)
    const float bi0 = bias[hcol0 + j0],         bi1 = bias[hcol0 + j0 + 1];
    const float bf0 = bias[512  + hcol0 + j0],  bf1 = bias[512  + hcol0 + j0 + 1];
    const float bg0 = bias[1024 + hcol0 + j0],  bg1 = bias[1024 + hcol0 + j0 + 1];
    const float bo0 = bias[1536 + hcol0 + j0],  bo1 = bias[1536 + hcol0 + j0 + 1];
    float cc0 = 0.f, cc1 = 0.f;

    unsigned int* rowflags = flags + r * 64;   // 16 blocks x 4 waves
    const int arow = L & 15;
    const int agrp = L >> 4;
    char* ldsb = reinterpret_cast<char*>(Alds);
    const int ard = arow * 1024;
    const int asw = (arow & 7) << 4;

    for (int t = 0; t < S_; ++t) {
        // ---- 1. x fragment prefetch (K tiles 16..19) — plain loads, fly during poll
        V16 xf[4];
        const _Float16* xp = xbuf + ((size_t)t * B_ + brow0 + arow) * KX + (agrp << 3);
#pragma unroll
        for (int j = 0; j < 4; ++j)
            xf[j].f = *reinterpret_cast<const f32x4*>(xp + j * 32);

        if (t > 0) {
            // ---- 2. poll: lane L waits on flag L (16 blocks x 4 waves)
            int polls = 0;
            while (__hip_atomic_load(&rowflags[L], __ATOMIC_RELAXED,
                                     __HIP_MEMORY_SCOPE_AGENT) < (unsigned)t) {
                if (++polls > 20000000) break;   // safety valve (never trips when correct)
            }
            __builtin_amdgcn_sched_barrier(0);

            // ---- 3. stage h_t tile -> LDS. 2048 u64, lane-contiguous loads (LLC-direct)
            const unsigned long long* hq = reinterpret_cast<const unsigned long long*>(
                hbuf + ((t & 1) ? (size_t)(B_ * H_) : 0) + (size_t)brow0 * H_);
#pragma unroll
            for (int j = 0; j < 8; ++j) {
                unsigned long long hv = __hip_atomic_load(hq + j * 256 + tid,
                        __ATOMIC_RELAXED, __HIP_MEMORY_SCOPE_AGENT);
                // u64 idx = j*256+tid -> row = idx>>7, col(u64) = idx&127
                const int row = (j << 1) + (tid >> 7);
                const int col = tid & 127;
                *reinterpret_cast<unsigned long long*>(
                    ldsb + row * 1024 + ((((col >> 1) << 4) ^ ((row & 7) << 4)))
                         + ((col & 1) << 3)) = hv;
            }
        }
        __syncthreads();                       // barrier 1: h tile ready

        // ---- 4. MFMA: wave w = gate-type w, 2 ntiles, 4 acc chains
        f32x4 a00 = {0,0,0,0}, a01 = {0,0,0,0}, a10 = {0,0,0,0}, a11 = {0,0,0,0};
#pragma unroll
        for (int j = 0; j < 4; ++j) {          // x part: K tiles 16..19
            half8 a = xf[j].h;
            if (j & 1) {
                a01 = __builtin_amdgcn_mfma_f32_16x16x32_f16(a, h8(bfrag[0][16 + j]), a01, 0, 0, 0);
                a11 = __builtin_amdgcn_mfma_f32_16x16x32_f16(a, h8(bfrag[1][16 + j]), a11, 0, 0, 0);
            } else {
                a00 = __builtin_amdgcn_mfma_f32_16x16x32_f16(a, h8(bfrag[0][16 + j]), a00, 0, 0, 0);
                a10 = __builtin_amdgcn_mfma_f32_16x16x32_f16(a, h8(bfrag[1][16 + j]), a10, 0, 0, 0);
            }
        }
        if (t > 0) {                           // h part: K tiles 0..15
#pragma unroll
            for (int kt = 0; kt < 16; ++kt) {
                half8 a = *reinterpret_cast<const half8*>(
                    ldsb + ard + ((((kt << 2) + agrp) << 4) ^ asw));
                if (kt & 1) {
                    a01 = __builtin_amdgcn_mfma_f32_16x16x32_f16(a, h8(bfrag[0][kt]), a01, 0, 0, 0);
                    a11 = __builtin_amdgcn_mfma_f32_16x16x32_f16(a, h8(bfrag[1][kt]), a11, 0, 0, 0);
                } else {
                    a00 = __builtin_amdgcn_mfma_f32_16x16x32_f16(a, h8(bfrag[0][kt]), a00, 0, 0, 0);
                    a10 = __builtin_amdgcn_mfma_f32_16x16x32_f16(a, h8(bfrag[1][kt]), a10, 0, 0, 0);
                }
            }
        }
        f32x4 g0 = a00 + a01;
        f32x4 g1 = a10 + a11;
        {
            const int grb = agrp << 2;         // C/D: col=lane&15, row=(lane>>4)*4+reg
            const int gc  = L & 15;
#pragma unroll
            for (int rr = 0; rr < 4; ++rr) {
                gbuf[w][grb + rr][gc]      = g0[rr];
                gbuf[w][grb + rr][16 + gc] = g1[rr];
            }
        }
        __syncthreads();                       // barrier 2: gates ready

        // ---- 5. elementwise LSTM cell update (2 values/thread, c in regs)
        float i0 = gbuf[0][bl][j0]     + bi0, i1 = gbuf[0][bl][j0 + 1] + bi1;
        float f0 = gbuf[1][bl][j0]     + bf0, f1 = gbuf[1][bl][j0 + 1] + bf1;
        float gg0= gbuf[2][bl][j0]     + bg0, gg1= gbuf[2][bl][j0 + 1] + bg1;
        float o0 = gbuf[3][bl][j0]     + bo0, o1 = gbuf[3][bl][j0 + 1] + bo1;
        float si0 = 1.f / (1.f + __expf(-i0));
        float sf0 = 1.f / (1.f + __expf(-f0));
        float so0 = 1.f / (1.f + __expf(-o0));
        float tg0 = tanhf(gg0);
        float si1 = 1.f / (1.f + __expf(-i1));
        float sf1 = 1.f / (1.f + __expf(-f1));
        float so1 = 1.f / (1.f + __expf(-o1));
        float tg1 = tanhf(gg1);
        cc0 = sf0 * cc0 + si0 * tg0;
        cc1 = sf1 * cc1 + si1 * tg1;
        float h0 = so0 * tanhf(cc0);
        float h1 = so1 * tanhf(cc1);

        if (t == S_ - 1) {
            float* op = out + (size_t)(brow0 + bl) * H_ + hcol0 + j0;
            op[0] = h0; op[1] = h1;
        } else {
            // ---- 6. publish h_{t+1} (LLC-direct) + per-wave release flag
            _Float16 hh0 = (_Float16)h0, hh1 = (_Float16)h1;
            unsigned int pack = ((unsigned int)*(unsigned short*)&hh1 << 16)
                              |  (unsigned int)*(unsigned short*)&hh0;
            unsigned int* hp = reinterpret_cast<unsigned int*>(
                hbuf + (((t + 1) & 1) ? (size_t)(B_ * H_) : 0)
                     + (size_t)(brow0 + bl) * H_ + hcol0 + j0);
            __hip_atomic_store(hp, pack, __ATOMIC_RELAXED, __HIP_MEMORY_SCOPE_AGENT);
            if (L == 0)   // release: drains this wave's vmcnt, then flag -> LLC
                __hip_atomic_store(&rowflags[(c << 2) + w], (unsigned)(t + 1),
                                   __ATOMIC_RELEASE, __HIP_MEMORY_SCOPE_AGENT);
        }
    }
}

// ---------------------------------------------------------------- launch
extern "C" void kernel_launch(void* const* d_in, const int* in_sizes, int n_in,
                              void* d_out, int out_size, void* d_ws, size_t ws_size,
                              hipStream_t stream) {
    (void)in_sizes; (void)n_in; (void)out_size;
    if (ws_size < WS_NEED) return;

    const int*   sent = (const int*)d_in[0];
    const float* emb  = (const float*)d_in[1];
    const float* Wih  = (const float*)d_in[2];
    const float* Whh  = (const float*)d_in[3];
    const float* bih  = (const float*)d_in[4];
    const float* bhh  = (const float*)d_in[5];

    char* ws = (char*)d_ws;
    _Float16*     Wc    = (_Float16*)(ws + OFF_WC);
    _Float16*     hbuf  = (_Float16*)(ws + OFF_HBUF);
    _Float16*     xbuf  = (_Float16*)(ws + OFF_XBUF);
    float*        bias  = (float*)(ws + OFF_BIAS);
    unsigned int* flags = (unsigned int*)(ws + OFF_FLAG);

    hipMemsetAsync(flags, 0, 16 * 64 * sizeof(unsigned int), stream);
    // no hbuf init needed: t=0 computes x-only gates, h_1 is written before any read

    prep_wc<<<(G_ * K_) / 256, 256, 0, stream>>>(Wih, Whh, bih, bhh, Wc, bias);
    prep_x<<<(S_ * B_ * KX) / 256, 256, 0, stream>>>(sent, emb, xbuf);
    lstm_persist<<<256, 256, 0, stream>>>(Wc, hbuf, xbuf, bias, flags, (float*)d_out);
}

// Round 4
// 3209.867 us; speedup vs baseline: 3.1744x; 3.1744x over previous
//
#include <hip/hip_runtime.h>
#include <stdint.h>

// Problem constants
#define B_  256
#define S_  512
#define E_  100
#define H_  512
#define G_  2048          // 4H
#define KH  512           // h part of K
#define KX  128           // padded x part of K
#define K_  640           // KH + KX

typedef _Float16 half8 __attribute__((ext_vector_type(8)));
typedef float    f32x4 __attribute__((ext_vector_type(4)));

union V16 { f32x4 f; half8 h; };

// ws layout (bytes)
#define OFF_WC   0u          // Wc2 fragment-major [c16][w4][n2][kt20][L64][e8] f16 : 2,621,440
#define OFF_HBUF 2621440u    // [2][B][H] f16    :   524,288
#define OFF_XBUF 3145728u    // xbuf2 [t512][rg16][j4][L64][e8] f16 : 33,554,432
#define OFF_BIAS 36700160u   // [G] f32          :     8,192
#define OFF_CNT  36708352u   // [16 rows][32] u32, one counter per row padded to 128B : 2,048
#define WS_NEED  36710400u

// LDS carve (dynamic): W h-part + A tile + gate buffer
#define LDS_W   131072       // [w4][n2][kt16][L64][16B]
#define LDS_A   16384        // h A-tile [16 rows][512 halfs], XOR-swizzled
#define LDS_G   8448         // float[4][16][33]
#define LDS_TOT (LDS_W + LDS_A + LDS_G)   // 155,904 < 160 KiB

// ---------------------------------------------------------------- prep: W (fragment-major) + bias
// Wc2 idx = ((((c*4 + w)*2 + n)*20 + kt)*64 + L)*8 + e
//   gate-row g = w*512 + c*32 + n*16 + (L&15);  k = kt*32 + (L>>4)*8 + e
__global__ void prep_wc2(const float* __restrict__ Wih, const float* __restrict__ Whh,
                         const float* __restrict__ bih, const float* __restrict__ bhh,
                         _Float16* __restrict__ Wc2, float* __restrict__ bias) {
    int idx = blockIdx.x * 256 + threadIdx.x;     // < G_*K_ = 1,310,720
    int e  = idx & 7;
    int L  = (idx >> 3) & 63;
    int q  = idx >> 9;                            // < 2560
    int kt = q % 20;
    int qq = q / 20;
    int nn = qq & 1;
    int w  = (qq >> 1) & 3;
    int cc = qq >> 3;
    int g  = (w << 9) + (cc << 5) + (nn << 4) + (L & 15);
    int k  = (kt << 5) + ((L >> 4) << 3) + e;
    float v = 0.f;
    if (k < KH)               v = Whh[g * KH + k];
    else if ((k - KH) < E_)   v = Wih[g * E_ + (k - KH)];
    Wc2[idx] = (_Float16)v;
    if (idx < G_) bias[idx] = bih[idx] + bhh[idx];
}

// ---------------------------------------------------------------- prep: embed gather (fragment-major)
// xbuf2 idx = (((t*16 + rg)*4 + j)*64 + L)*8 + e ; batch = rg*16+(L&15), k = j*32+(L>>4)*8+e
__global__ void prep_x2(const int* __restrict__ sent, const float* __restrict__ emb,
                        _Float16* __restrict__ xbuf2) {
    size_t idx = (size_t)blockIdx.x * 256 + threadIdx.x;  // < 2^24
    int e  = (int)(idx & 7);
    int L  = (int)((idx >> 3) & 63);
    int j  = (int)((idx >> 9) & 3);
    int rg = (int)((idx >> 11) & 15);
    int t  = (int)(idx >> 15);
    int b  = (rg << 4) + (L & 15);
    int k  = (j << 5) + ((L >> 4) << 3) + e;
    int tok = sent[b * S_ + t];
    float v = (k < E_) ? emb[(size_t)tok * E_ + k] : 0.f;
    xbuf2[idx] = (_Float16)v;
}

// ---------------------------------------------------------------- persistent LSTM
// 256 blocks = 16 batch-rows x 16 hcol-tiles; block owns [16 batch x 32 hcol].
// W h-part lives in LDS (loaded once); W x-part in regs. Cross-block h via
// agent-scope (LLC-direct) atomics. Sync: one padded counter per row;
// producers barrier-drain + single release fetch_add; consumers per-wave
// uniform poll (coalesced, s_sleep backoff) -> airtight per-wave ordering.
__global__ __launch_bounds__(256, 1) void lstm_persist(
    const _Float16* __restrict__ Wc2, _Float16* __restrict__ hbuf,
    const _Float16* __restrict__ xbuf2, const float* __restrict__ bias,
    unsigned int* __restrict__ cnts, float* __restrict__ out)
{
    extern __shared__ __align__(16) char smem[];
    char* wl = smem;                       // W h-part fragments
    char* al = smem + LDS_W;               // A tile (swizzled)
    float (*gbuf)[16][33] = reinterpret_cast<float(*)[16][33]>(smem + LDS_W + LDS_A);

    const int tid = threadIdx.x;
    const int L   = tid & 63;
    const int w   = tid >> 6;              // wave = gate type (0:i 1:f 2:g 3:o)
    const int bx  = blockIdx.x;
    const int xcd = bx & 7;                // XCD-aware swizzle (perf heuristic only)
    const int kk_ = bx >> 3;
    const int r   = (xcd << 1) | (kk_ >> 4);   // batch-row 0..15
    const int c   = kk_ & 15;                  // hcol-tile 0..15
    const int brow0 = r << 4;
    const int hcol0 = c << 5;

    // ---- W preload. Fragment base for (c, w): two n-tiles of [20 kt][64 L][8]
    const _Float16* wp0 = Wc2 + ((size_t)(((c << 2) + w) << 1)) * (20 * 512) + (L << 3);
    const _Float16* wp1 = wp0 + 20 * 512;
    // h-part (kt 0..15) -> LDS, per-wave private region [((w*2+n)*16+kt)*1024 + L*16]
#pragma unroll
    for (int n = 0; n < 2; ++n)
#pragma unroll
        for (int kt = 0; kt < 16; ++kt) {
            f32x4 v = *reinterpret_cast<const f32x4*>((n ? wp1 : wp0) + (kt << 9));
            *reinterpret_cast<f32x4*>(wl + ((((w << 1) + n) * 16 + kt) << 10) + (L << 4)) = v;
        }
    // x-part (kt 16..19) -> regs (8 x f32x4 = 32 VGPRs)
    V16 wx[2][4];
#pragma unroll
    for (int n = 0; n < 2; ++n)
#pragma unroll
        for (int j = 0; j < 4; ++j)
            wx[n][j].f = *reinterpret_cast<const f32x4*>((n ? wp1 : wp0) + ((16 + j) << 9));

    // ---- per-thread cell-state mapping: thread owns h/c values v0=2*tid, v0+1
    const int v0 = tid << 1;
    const int bl = v0 >> 5;
    const int j0 = v0 & 31;
    const float bi0 = bias[hcol0 + j0],         bi1 = bias[hcol0 + j0 + 1];
    const float bf0 = bias[512  + hcol0 + j0],  bf1 = bias[512  + hcol0 + j0 + 1];
    const float bg0 = bias[1024 + hcol0 + j0],  bg1 = bias[1024 + hcol0 + j0 + 1];
    const float bo0 = bias[1536 + hcol0 + j0],  bo1 = bias[1536 + hcol0 + j0 + 1];
    float cc0 = 0.f, cc1 = 0.f;

    unsigned int* cnt = cnts + r * 32;     // padded row counter (128B apart)
    const int arow = L & 15;
    const int agrp = L >> 4;
    const int ard  = arow << 10;
    const int asw  = (arow & 7) << 4;

    for (int t = 0; t < S_; ++t) {
        // ---- 1. x fragments (coalesced 1KB wave-loads, call-constant data)
        V16 xf[4];
        const _Float16* xp = xbuf2 + (((size_t)t * 16 + r) * 4) * 512 + (L << 3);
#pragma unroll
        for (int j = 0; j < 4; ++j)
            xf[j].f = *reinterpret_cast<const f32x4*>(xp + j * 512);

        // ---- 2. x-part MFMA first — independent of h, runs before/during sync
        f32x4 a00 = {0,0,0,0}, a01 = {0,0,0,0}, a10 = {0,0,0,0}, a11 = {0,0,0,0};
#pragma unroll
        for (int j = 0; j < 4; ++j) {
            if (j & 1) {
                a01 = __builtin_amdgcn_mfma_f32_16x16x32_f16(xf[j].h, wx[0][j].h, a01, 0, 0, 0);
                a11 = __builtin_amdgcn_mfma_f32_16x16x32_f16(xf[j].h, wx[1][j].h, a11, 0, 0, 0);
            } else {
                a00 = __builtin_amdgcn_mfma_f32_16x16x32_f16(xf[j].h, wx[0][j].h, a00, 0, 0, 0);
                a10 = __builtin_amdgcn_mfma_f32_16x16x32_f16(xf[j].h, wx[1][j].h, a10, 0, 0, 0);
            }
        }

        if (t > 0) {
            // ---- 3. per-wave uniform poll (all 64 lanes same addr -> 1 request)
            unsigned int polls = 0;
            while (__hip_atomic_load(cnt, __ATOMIC_RELAXED,
                                     __HIP_MEMORY_SCOPE_AGENT) < 16u * (unsigned)t) {
                __builtin_amdgcn_s_sleep(1);
                if (++polls > 100000000u) break;   // safety valve
            }
            __builtin_amdgcn_sched_barrier(0);

            // ---- 4. this wave stages its quarter (control-dependent on ITS poll)
            const unsigned long long* hq = reinterpret_cast<const unsigned long long*>(
                hbuf + ((t & 1) ? (size_t)(B_ * H_) : 0) + (size_t)brow0 * H_);
#pragma unroll
            for (int i = 0; i < 8; ++i) {
                const int q = (w << 9) + (i << 6) + L;      // u64 idx in [16][128] tile
                unsigned long long hv = __hip_atomic_load(hq + q,
                        __ATOMIC_RELAXED, __HIP_MEMORY_SCOPE_AGENT);
                const int row = q >> 7;
                const int col = q & 127;
                *reinterpret_cast<unsigned long long*>(
                    al + (row << 10) + ((((col >> 1) << 4) ^ ((row & 7) << 4)))
                       + ((col & 1) << 3)) = hv;
            }
        }
        __syncthreads();                   // barrier 1: A tile ready (all waves)

        // ---- 5. h-part MFMA: B from LDS (contiguous 16B/lane), A from swizzled LDS
        if (t > 0) {
#pragma unroll
            for (int kt = 0; kt < 16; ++kt) {
                V16 av, b0, b1;
                av.f = *reinterpret_cast<const f32x4*>(
                    al + ard + ((((kt << 2) + agrp) << 4) ^ asw));
                b0.f = *reinterpret_cast<const f32x4*>(wl + (((w << 5) + kt) << 10) + (L << 4));
                b1.f = *reinterpret_cast<const f32x4*>(wl + (((w << 5) + 16 + kt) << 10) + (L << 4));
                if (kt & 1) {
                    a01 = __builtin_amdgcn_mfma_f32_16x16x32_f16(av.h, b0.h, a01, 0, 0, 0);
                    a11 = __builtin_amdgcn_mfma_f32_16x16x32_f16(av.h, b1.h, a11, 0, 0, 0);
                } else {
                    a00 = __builtin_amdgcn_mfma_f32_16x16x32_f16(av.h, b0.h, a00, 0, 0, 0);
                    a10 = __builtin_amdgcn_mfma_f32_16x16x32_f16(av.h, b1.h, a10, 0, 0, 0);
                }
            }
        }
        f32x4 g0 = a00 + a01;
        f32x4 g1 = a10 + a11;
        {
            const int grb = agrp << 2;     // C/D: col=lane&15, row=(lane>>4)*4+reg
            const int gc  = L & 15;
#pragma unroll
            for (int rr = 0; rr < 4; ++rr) {
                gbuf[w][grb + rr][gc]      = g0[rr];
                gbuf[w][grb + rr][16 + gc] = g1[rr];
            }
        }
        __syncthreads();                   // barrier 2: gates ready

        // ---- 6. elementwise cell update (2 values/thread, c in regs)
        float i0 = gbuf[0][bl][j0]     + bi0, i1 = gbuf[0][bl][j0 + 1] + bi1;
        float f0 = gbuf[1][bl][j0]     + bf0, f1 = gbuf[1][bl][j0 + 1] + bf1;
        float gg0= gbuf[2][bl][j0]     + bg0, gg1= gbuf[2][bl][j0 + 1] + bg1;
        float o0 = gbuf[3][bl][j0]     + bo0, o1 = gbuf[3][bl][j0 + 1] + bo1;
        float si0 = 1.f / (1.f + __expf(-i0));
        float sf0 = 1.f / (1.f + __expf(-f0));
        float so0 = 1.f / (1.f + __expf(-o0));
        float tg0 = tanhf(gg0);
        float si1 = 1.f / (1.f + __expf(-i1));
        float sf1 = 1.f / (1.f + __expf(-f1));
        float so1 = 1.f / (1.f + __expf(-o1));
        float tg1 = tanhf(gg1);
        cc0 = sf0 * cc0 + si0 * tg0;
        cc1 = sf1 * cc1 + si1 * tg1;
        float h0 = so0 * tanhf(cc0);
        float h1 = so1 * tanhf(cc1);

        if (t == S_ - 1) {
            float* op = out + (size_t)(brow0 + bl) * H_ + hcol0 + j0;
            op[0] = h0; op[1] = h1;
        } else {
            // ---- 7. publish h_{t+1} (LLC-direct), drain ALL waves at barrier,
            //         then ONE release fetch_add per block on the row counter.
            _Float16 hh0 = (_Float16)h0, hh1 = (_Float16)h1;
            unsigned int pack = ((unsigned int)*(unsigned short*)&hh1 << 16)
                              |  (unsigned int)*(unsigned short*)&hh0;
            unsigned int* hp = reinterpret_cast<unsigned int*>(
                hbuf + (((t + 1) & 1) ? (size_t)(B_ * H_) : 0)
                     + (size_t)(brow0 + bl) * H_ + hcol0 + j0);
            __hip_atomic_store(hp, pack, __ATOMIC_RELAXED, __HIP_MEMORY_SCOPE_AGENT);
            __syncthreads();               // barrier 3: every wave's vmcnt drained
            if (tid == 0)
                (void)__hip_atomic_fetch_add(cnt, 1u, __ATOMIC_RELEASE,
                                             __HIP_MEMORY_SCOPE_AGENT);
        }
    }
}

// ---------------------------------------------------------------- launch
extern "C" void kernel_launch(void* const* d_in, const int* in_sizes, int n_in,
                              void* d_out, int out_size, void* d_ws, size_t ws_size,
                              hipStream_t stream) {
    (void)in_sizes; (void)n_in; (void)out_size;
    if (ws_size < WS_NEED) return;

    const int*   sent = (const int*)d_in[0];
    const float* emb  = (const float*)d_in[1];
    const float* Wih  = (const float*)d_in[2];
    const float* Whh  = (const float*)d_in[3];
    const float* bih  = (const float*)d_in[4];
    const float* bhh  = (const float*)d_in[5];

    char* ws = (char*)d_ws;
    _Float16*     Wc2   = (_Float16*)(ws + OFF_WC);
    _Float16*     hbuf  = (_Float16*)(ws + OFF_HBUF);
    _Float16*     xbuf2 = (_Float16*)(ws + OFF_XBUF);
    float*        bias  = (float*)(ws + OFF_BIAS);
    unsigned int* cnts  = (unsigned int*)(ws + OFF_CNT);

    // host-side attribute set (not a stream op; persists from first call)
    (void)hipFuncSetAttribute(reinterpret_cast<const void*>(lstm_persist),
                              hipFuncAttributeMaxDynamicSharedMemorySize, LDS_TOT);

    hipMemsetAsync(cnts, 0, 16 * 32 * sizeof(unsigned int), stream);

    prep_wc2<<<(G_ * K_) / 256, 256, 0, stream>>>(Wih, Whh, bih, bhh, Wc2, bias);
    prep_x2<<<(S_ * B_ * KX) / 256, 256, 0, stream>>>(sent, emb, xbuf2);
    lstm_persist<<<256, 256, LDS_TOT, stream>>>(Wc2, hbuf, xbuf2, bias, cnts, (float*)d_out);
}